// Round 8
// baseline (228.060 us; speedup 1.0000x reference)
//
#include <hip/hip_runtime.h>
#include <hip/hip_bf16.h>

#define BATCH 8
#define NQ 3136
#define CDIM 128
#define NHEAD 4
#define HD 32
#define NKV 784
#define HIMG 56
#define SCALE 0.17677669529663687f

typedef __attribute__((ext_vector_type(8))) short bf8_t;   // 8 x bf16 (4 VGPRs)
typedef __attribute__((ext_vector_type(4))) float f4_t;    // 4 x fp32

using bf16 = __hip_bfloat16;
using u16  = unsigned short;

static __device__ __forceinline__ float b2f(bf16 v){ return __bfloat162float(v); }
static __device__ __forceinline__ bf16  f2b(float v){ return __float2bfloat16(v); }
static __device__ __forceinline__ short f2s(float v){
  union { bf16 b; short s; } u; u.b = f2b(v); return u.s;
}
static __device__ __forceinline__ float u16f(u16 x){
  union { u16 u; bf16 b; } c; c.u = x; return b2f(c.b);
}
// dual-dtype scalar load: f=1 -> bf16, f=0 -> fp32
static __device__ __forceinline__ float ld1(const void* p, size_t i, int f){
  return f ? b2f(((const bf16*)p)[i]) : ((const float*)p)[i];
}
// dual-dtype 4-element load (8B bf16 / 16B fp32)
static __device__ __forceinline__ float4 ld4f(const void* p, size_t i, int f){
  if (f){
    ushort4 u = *(const ushort4*)((const bf16*)p + i);
    return make_float4(u16f(u.x), u16f(u.y), u16f(u.z), u16f(u.w));
  }
  return *(const float4*)((const float*)p + i);
}
// dual-dtype 8-element fragment load (16B-aligned in both modes)
static __device__ __forceinline__ bf8_t ld8(const void* p, size_t i, int f){
  if (f) return *(const bf8_t*)((const bf16*)p + i);
  const float* fp = (const float*)p + i;
  float4 a = *(const float4*)fp;
  float4 b = *(const float4*)(fp + 4);
  bf8_t r;
  r[0]=f2s(a.x); r[1]=f2s(a.y); r[2]=f2s(a.z); r[3]=f2s(a.w);
  r[4]=f2s(b.x); r[5]=f2s(b.y); r[6]=f2s(b.z); r[7]=f2s(b.w);
  return r;
}
// Inline dtype detect from bn_var (~U[0.5,1.5]); wave-uniform, ~free (256B L2-hot).
static __device__ __forceinline__ int detect_flag(const void* var_raw){
  const u16* h = (const u16*)var_raw;
  int lane = threadIdx.x & 63;
  bool ok = true;
  #pragma unroll
  for (int t = 0; t < 2; t++){
    union { u16 u; bf16 b; } cv; cv.u = h[lane + 64*t];
    float v = b2f(cv.b);
    ok = ok && (v > 0.3f) && (v < 1.7f);
  }
  return (__ballot(ok) == ~0ull) ? 1 : 0;
}

// shared MFMA row core: acc[8] (16 rows x 128 cols) from prepped A-frags
static __device__ __forceinline__ void mfma_row(
    const bf8_t a[4], const bf16* __restrict__ Wt, int m, int g, f4_t acc[8])
{
  #pragma unroll
  for (int ct = 0; ct < 8; ct++){
    f4_t c = {0.f,0.f,0.f,0.f};
    const bf16* bp = Wt + (size_t)(ct*16 + m)*CDIM + 8*g;
    #pragma unroll
    for (int ks = 0; ks < 4; ks++){
      bf8_t b = *(const bf8_t*)(bp + 32*ks);
      c = __builtin_amdgcn_mfma_f32_16x16x32_bf16(a[ks], b, c, 0,0,0);
    }
    acc[ct] = c;
  }
}

// ---------------------------------------------------------------------------
// prep: weight transposes, SCALE folded into Wqt/bqs; small params; BN fold.
// cwf stored transposed [k][c] (k=tap 0..3, c=channel) for float4 loads.
// ---------------------------------------------------------------------------
__global__ __launch_bounds__(256) void prep_kernel(
    const void* __restrict__ Wq, const void* __restrict__ Wk,
    const void* __restrict__ Wv, const void* __restrict__ Wp,
    const void* __restrict__ var, const void* __restrict__ cw,
    const void* __restrict__ cb, const void* __restrict__ gam,
    const void* __restrict__ bet, const void* __restrict__ mea,
    const void* __restrict__ bq, const void* __restrict__ bk,
    const void* __restrict__ bv, const void* __restrict__ bp,
    bf16* __restrict__ Wqt, bf16* __restrict__ Wkt,
    bf16* __restrict__ Wvt, bf16* __restrict__ Wpt,
    bf16* __restrict__ bqs, bf16* __restrict__ bks,
    bf16* __restrict__ bvs, bf16* __restrict__ bps,
    float* __restrict__ cwf, float* __restrict__ inv, float* __restrict__ shift2)
{
  int f = detect_flag(var);
  int idx = blockIdx.x*256 + threadIdx.x;   // 4 * 16384
  int mat = idx >> 14;
  int e   = idx & 16383;                    // dst element: o=e>>7, i=e&127
  int o = e >> 7, i = e & 127;
  const void* src; bf16* dst; float s = 1.f;
  if      (mat == 0){ src = Wq; dst = Wqt; s = SCALE; }
  else if (mat == 1){ src = Wk; dst = Wkt; }
  else if (mat == 2){ src = Wv; dst = Wvt; }
  else              { src = Wp; dst = Wpt; }
  dst[e] = f2b(ld1(src, (size_t)i*128 + o, f) * s);

  if (blockIdx.x == 0){
    int t = threadIdx.x;
    // cw layout (C,1,2,2) = c*4+k  ->  cwf[k*128 + c]
    { int e2 = t;       cwf[(e2&3)*128 + (e2>>2)] = ld1(cw, e2, f); }
    { int e2 = t + 256; cwf[(e2&3)*128 + (e2>>2)] = ld1(cw, e2, f); }
    if (t < 128){
      bqs[t] = f2b(ld1(bq, t, f) * SCALE);
      bks[t] = f2b(ld1(bk, t, f));
      bvs[t] = f2b(ld1(bv, t, f));
      bps[t] = f2b(ld1(bp, t, f));
      float iv = ld1(gam, t, f) * rsqrtf(ld1(var, t, f) + 1e-5f);
      inv[t] = iv;
      shift2[t] = ld1(bet, t, f) - ld1(mea, t, f) * iv + ld1(cb, t, f) * iv;
    }
  }
}

// ---------------------------------------------------------------------------
// kvconv: fused conv2x2s2+BN (64 rows -> LDS, padded stride 136) + K and V
// projections from LDS. 98 blocks x 256. Replaces fat's conv + kv_kernel;
// xr never touches global memory.
// ---------------------------------------------------------------------------
__global__ __launch_bounds__(256) void kvconv_kernel(
    const void* __restrict__ x, const void* __restrict__ var,
    const float* __restrict__ cwf, const float* __restrict__ inv,
    const float* __restrict__ shift2,
    const bf16* __restrict__ Wkt, const bf16* __restrict__ Wvt,
    const bf16* __restrict__ bks, const bf16* __restrict__ bvs,
    bf16* __restrict__ kbf, bf16* __restrict__ vtb)
{
  int f = detect_flag(var);
  __shared__ bf16 xl[64*136];          // 17408 B, padded stride kills GEMM-read conflicts
  int row0 = blockIdx.x*64;            // global row = b*NKV + kv

  #pragma unroll
  for (int it = 0; it < 8; it++){
    int s  = it*256 + threadIdx.x;     // 0..2047 = 64 rows x 32 ch-groups
    int lr = s >> 5;
    int c0 = (s & 31)*4;
    int t  = row0 + lr;
    int b  = t / NKV;
    int kv = t - b*NKV;
    int i = kv/28, j = kv - i*28;
    size_t base = (size_t)(b*NQ + 2*i*HIMG + 2*j)*CDIM + c0;
    float4 t0 = ld4f(x, base, f);
    float4 t1 = ld4f(x, base + CDIM, f);
    float4 t2 = ld4f(x, base + HIMG*CDIM, f);
    float4 t3 = ld4f(x, base + HIMG*CDIM + CDIM, f);
    float4 w0 = *(const float4*)(cwf + c0);
    float4 w1 = *(const float4*)(cwf + 128 + c0);
    float4 w2 = *(const float4*)(cwf + 256 + c0);
    float4 w3 = *(const float4*)(cwf + 384 + c0);
    float4 iv4 = *(const float4*)(inv + c0);
    float4 sh4 = *(const float4*)(shift2 + c0);
    union { u16 h[4]; uint2 u; } pk;
    float a;
    a = t0.x*w0.x + t1.x*w1.x + t2.x*w2.x + t3.x*w3.x; pk.h[0] = (u16)f2s(a*iv4.x + sh4.x);
    a = t0.y*w0.y + t1.y*w1.y + t2.y*w2.y + t3.y*w3.y; pk.h[1] = (u16)f2s(a*iv4.y + sh4.y);
    a = t0.z*w0.z + t1.z*w1.z + t2.z*w2.z + t3.z*w3.z; pk.h[2] = (u16)f2s(a*iv4.z + sh4.z);
    a = t0.w*w0.w + t1.w*w1.w + t2.w*w2.w + t3.w*w3.w; pk.h[3] = (u16)f2s(a*iv4.w + sh4.w);
    *(uint2*)(xl + lr*136 + c0) = pk.u;
  }
  __syncthreads();

  int wave = threadIdx.x >> 6, lane = threadIdx.x & 63;
  int m = lane & 15, g = lane >> 4;
  int r16 = wave*16;                   // local row base; 16-row tasks never straddle b
  bf8_t a[4];
  #pragma unroll
  for (int ks = 0; ks < 4; ks++)
    a[ks] = *(const bf8_t*)(xl + (r16 + m)*136 + 8*g + 32*ks);
  int grow = row0 + r16;

  {  // K projection -> kbf (B*NKV, C)
    f4_t acc[8];
    mfma_row(a, Wkt, m, g, acc);
    #pragma unroll
    for (int ct = 0; ct < 8; ct++){
      int col = ct*16 + m;
      float bv = b2f(bks[col]);
      #pragma unroll
      for (int r = 0; r < 4; r++)
        kbf[(size_t)(grow + 4*g + r)*CDIM + col] = f2b(acc[ct][r] + bv);
    }
  }
  {  // V projection -> vtb transposed (B,H,D,NKV)
    f4_t acc[8];
    mfma_row(a, Wvt, m, g, acc);
    int b2  = grow / NKV;
    int kv0 = grow - b2*NKV + 4*g;
    #pragma unroll
    for (int ct = 0; ct < 8; ct++){
      int col = ct*16 + m;
      float bv = b2f(bvs[col]);
      int h = col >> 5, d = col & 31;
      union { bf16 hh[4]; uint2 u; } pk;
      #pragma unroll
      for (int r = 0; r < 4; r++) pk.hh[r] = f2b(acc[ct][r] + bv);
      *(uint2*)(vtb + (size_t)((b2*NHEAD + h)*HD + d)*NKV + kv0) = pk.u;
    }
  }
}

// ---------------------------------------------------------------------------
// attn (r7 structure + fused Q-proj + direct rel reads, both dtypes):
// SWAPPED QK^T -> S^T = mfma(K,Q): lane (m,g) holds S[q=m][kv=kv0+16t+4g+r].
// Pipeline per 128-kv chunk: QK MFMAs (K prefetched last chunk) -> issue
// next-chunk K -> this-chunk V -> rel add (regs, prefetched) -> issue
// next-chunk rel -> defer-rescale softmax -> P pack -> wave-local LDS
// roundtrip -> PV. Zero barriers after the Q prologue. 1-wave blocks,
// grid (196,4,8): b-stride 784 % 8 == 0 -> batch-copies share an XCD L2.
// RM=1: rel bf16 (uint2/lane). RM=0: rel fp32 (float4/lane), no convert pass.
// ---------------------------------------------------------------------------
template<int RM> struct RelV { using T = float4; };
template<> struct RelV<1> { using T = uint2; };

template<int RM>
static __device__ __forceinline__ typename RelV<RM>::T relld(const void* relp, int off){
  if constexpr (RM == 1) return *(const uint2*)((const bf16*)relp + off);
  else                   return *(const float4*)((const float*)relp + off);
}
template<int RM>
static __device__ __forceinline__ float relget(const typename RelV<RM>::T& v, int r){
  if constexpr (RM == 1){
    union { uint2 u; u16 h[4]; } c; c.u = v;
    return u16f(c.h[r]);
  } else {
    return r == 0 ? v.x : (r == 1 ? v.y : (r == 2 ? v.z : v.w));
  }
}
template<int RM>
static __device__ __forceinline__ void ldrel8(
    typename RelV<RM>::T rl[8], const void* relp, int off){
  #pragma unroll
  for (int t = 0; t < 8; t++) rl[t] = relld<RM>(relp, off + 16*t);
}

// PF: 2 = prefetch full next chunk, 1 = prefetch tail (1 frag)
template<int RM, int PF>
static __device__ __forceinline__ void chunk128(
    int kv0,
    typename RelV<RM>::T rl[8], bf8_t kc[8],
    typename RelV<RM>::T rln[8], bf8_t kn[8],
    const void* __restrict__ relp, const bf16* __restrict__ kbase,
    const bf16* __restrict__ vb0, const bf16* __restrict__ vb1,
    bf16* __restrict__ pl, int m, int g, bf8_t q8,
    float& m_run, float& l_run, f4_t& O0, f4_t& O1)
{
  // QK^T from register K (prefetched during previous chunk)
  f4_t s[8];
  #pragma unroll
  for (int t = 0; t < 8; t++){
    f4_t z = {0.f,0.f,0.f,0.f};
    s[t] = __builtin_amdgcn_mfma_f32_16x16x32_bf16(kc[t], q8, z, 0,0,0);
  }
  // issue next-chunk K loads: latency hides under this chunk's softmax+PV
  if constexpr (PF == 2){
    #pragma unroll
    for (int t = 0; t < 8; t++)
      kn[t] = *(const bf8_t*)(kbase + (size_t)(kv0 + 128 + t*16)*CDIM);
  } else if constexpr (PF == 1){
    kn[0] = *(const bf8_t*)(kbase + (size_t)768*CDIM);
  }
  // this-chunk V: consumed after softmax (~200+ cy of slack)
  bf8_t v0[4], v1[4];
  #pragma unroll
  for (int ks = 0; ks < 4; ks++){
    v0[ks] = *(const bf8_t*)(vb0 + kv0 + ks*32 + 8*g);
    v1[ks] = *(const bf8_t*)(vb1 + kv0 + ks*32 + 8*g);
  }
  // rel add from prefetched registers; then issue next-chunk rel loads
  #pragma unroll
  for (int t = 0; t < 8; t++)
    #pragma unroll
    for (int r = 0; r < 4; r++)
      s[t][r] += relget<RM>(rl[t], r);
  if constexpr (PF == 2) ldrel8<RM>(rln, relp, kv0 + 128 + 4*g);
  else if constexpr (PF == 1) rln[0] = relld<RM>(relp, 768 + 4*g);
  // online softmax, one q (=m) per lane
  float vmax = s[0][0];
  #pragma unroll
  for (int t = 0; t < 8; t++)
    #pragma unroll
    for (int r = 0; r < 4; r++)
      if (t + r > 0) vmax = fmaxf(vmax, s[t][r]);
  vmax = fmaxf(vmax, __shfl_xor(vmax, 16, 64));
  vmax = fmaxf(vmax, __shfl_xor(vmax, 32, 64));
  // T13 defer-rescale: only rescale when the running max grows >THR.
  if (!__all(vmax <= m_run + 8.f)){
    float mn = fmaxf(m_run, vmax);
    float al = __expf(m_run - mn);
    m_run = mn;
    l_run *= al;
    float alT[4];
    #pragma unroll
    for (int r = 0; r < 4; r++) alT[r] = __shfl(al, 4*g + r, 64);
    #pragma unroll
    for (int r = 0; r < 4; r++){ O0[r] *= alT[r]; O1[r] *= alT[r]; }
  }
  // P: exp, lane-partial l, pack 4 bf16 -> b64 LDS write per t
  float lsum = 0.f;
  #pragma unroll
  for (int t = 0; t < 8; t++){
    union { u16 h[4]; uint2 u; } pk;
    #pragma unroll
    for (int r = 0; r < 4; r++){
      float p = __expf(s[t][r] - m_run);
      lsum += p;
      pk.h[r] = (u16)f2s(p);
    }
    *(uint2*)(pl + m*136 + t*16 + 4*g) = pk.u;
  }
  l_run += lsum;
  // PV: wave-local LDS roundtrip (same-wave in-order) + register V
  #pragma unroll
  for (int ks = 0; ks < 4; ks++){
    bf8_t a8 = *(const bf8_t*)(pl + m*136 + ks*32 + 8*g);
    O0 = __builtin_amdgcn_mfma_f32_16x16x32_bf16(a8, v0[ks], O0, 0,0,0);
    O1 = __builtin_amdgcn_mfma_f32_16x16x32_bf16(a8, v1[ks], O1, 0,0,0);
  }
}

template<int RM>
static __device__ __forceinline__ void attn_run(
    const void* __restrict__ relp, const bf16* __restrict__ kbase,
    const bf16* __restrict__ vb0, const bf16* __restrict__ vb1,
    bf16* __restrict__ pl, int m, int g,
    bf8_t q8, float& m_run, float& l_run, f4_t& O0, f4_t& O1)
{
  using RT = typename RelV<RM>::T;
  RT rlA[8], rlB[8];
  bf8_t kA[8], kB[8];
  ldrel8<RM>(rlA, relp, 4*g);
  #pragma unroll
  for (int t = 0; t < 8; t++)
    kA[t] = *(const bf8_t*)(kbase + (size_t)(t*16)*CDIM);

  chunk128<RM,2>(0,   rlA,kA, rlB,kB, relp,kbase,vb0,vb1,pl,m,g,q8,m_run,l_run,O0,O1);
  chunk128<RM,2>(128, rlB,kB, rlA,kA, relp,kbase,vb0,vb1,pl,m,g,q8,m_run,l_run,O0,O1);
  chunk128<RM,2>(256, rlA,kA, rlB,kB, relp,kbase,vb0,vb1,pl,m,g,q8,m_run,l_run,O0,O1);
  chunk128<RM,2>(384, rlB,kB, rlA,kA, relp,kbase,vb0,vb1,pl,m,g,q8,m_run,l_run,O0,O1);
  chunk128<RM,2>(512, rlA,kA, rlB,kB, relp,kbase,vb0,vb1,pl,m,g,q8,m_run,l_run,O0,O1);
  chunk128<RM,1>(640, rlB,kB, rlA,kA, relp,kbase,vb0,vb1,pl,m,g,q8,m_run,l_run,O0,O1);

  // ---- tail: kv 768..783 (K in kA[0], rel in rlA[0], prefetched) ----
  {
    f4_t z = {0.f,0.f,0.f,0.f};
    f4_t s1 = __builtin_amdgcn_mfma_f32_16x16x32_bf16(kA[0], q8, z, 0,0,0);
    #pragma unroll
    for (int r = 0; r < 4; r++) s1[r] += relget<RM>(rlA[0], r);
    float vmax = fmaxf(fmaxf(s1[0], s1[1]), fmaxf(s1[2], s1[3]));
    vmax = fmaxf(vmax, __shfl_xor(vmax, 16, 64));
    vmax = fmaxf(vmax, __shfl_xor(vmax, 32, 64));
    if (!__all(vmax <= m_run + 8.f)){
      float mn = fmaxf(m_run, vmax);
      float al = __expf(m_run - mn);
      m_run = mn;
      l_run *= al;
      float alT[4];
      #pragma unroll
      for (int r = 0; r < 4; r++) alT[r] = __shfl(al, 4*g + r, 64);
      #pragma unroll
      for (int r = 0; r < 4; r++){ O0[r] *= alT[r]; O1[r] *= alT[r]; }
    }
    union { u16 h[4]; uint2 u; } pk;
    float lsum = 0.f;
    #pragma unroll
    for (int r = 0; r < 4; r++){
      float p = __expf(s1[r] - m_run);
      lsum += p;
      pk.h[r] = (u16)f2s(p);
    }
    *(uint2*)(pl + m*136 + 4*g) = pk.u;
    l_run += lsum;
    bf8_t a8, v0, v1;
    if (g >= 2){        // kv >= 784: zero fragments in registers
      bf8_t z8 = {0,0,0,0,0,0,0,0};
      a8 = z8; v0 = z8; v1 = z8;
    } else {
      a8 = *(const bf8_t*)(pl + m*136 + 8*g);
      v0 = *(const bf8_t*)(vb0 + 768 + 8*g);
      v1 = *(const bf8_t*)(vb1 + 768 + 8*g);
    }
    O0 = __builtin_amdgcn_mfma_f32_16x16x32_bf16(a8, v0, O0, 0,0,0);
    O1 = __builtin_amdgcn_mfma_f32_16x16x32_bf16(a8, v1, O1, 0,0,0);
  }
}

__global__ __launch_bounds__(64) void attn_kernel(
    const void* __restrict__ x,
    const bf16* __restrict__ Wqt, const bf16* __restrict__ bqs,
    const bf16* __restrict__ kb, const bf16* __restrict__ vtb,
    const void* __restrict__ rel, const void* __restrict__ var,
    void* __restrict__ dout, bf16* __restrict__ obf)
{
  int f = detect_flag(var);
  int lane = threadIdx.x & 63;
  int m = lane & 15, g = lane >> 4;
  int qt = blockIdx.x, h = blockIdx.y, b = blockIdx.z;
  int qrow0 = qt*16;

  __shared__ bf16 Plds[16*136];   // 4352 B; wave-local
  bf16* pl = Plds;

  // fused Q projection (2 MFMAs + wave-local LDS roundtrip; no barrier)
  bf8_t q8;
  {
    bf8_t xa[4];
    #pragma unroll
    for (int ks = 0; ks < 4; ks++)
      xa[ks] = ld8(x, (size_t)(b*NQ + qrow0 + m)*CDIM + 8*g + 32*ks, f);
    f4_t qc0 = {0.f,0.f,0.f,0.f}, qc1 = {0.f,0.f,0.f,0.f};
    const bf16* wp0 = Wqt + (size_t)(h*HD + m)*CDIM + 8*g;
    const bf16* wp1 = Wqt + (size_t)(h*HD + 16 + m)*CDIM + 8*g;
    #pragma unroll
    for (int ks = 0; ks < 4; ks++){
      bf8_t w0 = *(const bf8_t*)(wp0 + 32*ks);
      bf8_t w1 = *(const bf8_t*)(wp1 + 32*ks);
      qc0 = __builtin_amdgcn_mfma_f32_16x16x32_bf16(xa[ks], w0, qc0, 0,0,0);
      qc1 = __builtin_amdgcn_mfma_f32_16x16x32_bf16(xa[ks], w1, qc1, 0,0,0);
    }
    float bv0 = b2f(bqs[h*HD + m]);
    float bv1 = b2f(bqs[h*HD + 16 + m]);
    #pragma unroll
    for (int r = 0; r < 4; r++){
      pl[(4*g + r)*136 + m]      = f2b(qc0[r] + bv0);
      pl[(4*g + r)*136 + 16 + m] = f2b(qc1[r] + bv1);
    }
    q8 = *(const bf8_t*)(pl + m*136 + 8*g);
  }

  const bf16* kbase = kb  + (size_t)(b*NKV + m)*CDIM + h*HD + 8*g;
  const bf16* vb0   = vtb + (size_t)((b*NHEAD + h)*HD + m)*NKV;
  const bf16* vb1   = vtb + (size_t)((b*NHEAD + h)*HD + 16 + m)*NKV;
  size_t rrow = ((size_t)h*NQ + qrow0 + m)*(size_t)NKV;   // per-lane q = m

  float m_run = -1e30f, l_run = 0.f;
  f4_t O0 = {0.f,0.f,0.f,0.f}, O1 = {0.f,0.f,0.f,0.f};

  if (f) attn_run<1>((const void*)((const bf16*)rel + rrow), kbase, vb0, vb1,
                     pl, m, g, q8, m_run, l_run, O0, O1);
  else   attn_run<0>((const void*)((const float*)rel + rrow), kbase, vb0, vb1,
                     pl, m, g, q8, m_run, l_run, O0, O1);

  // finalize: full l across g-lanes (q=m layout), transpose to O layout
  l_run += __shfl_xor(l_run, 16, 64);
  l_run += __shfl_xor(l_run, 32, 64);
  float lT[4];
  #pragma unroll
  for (int r = 0; r < 4; r++) lT[r] = __shfl(l_run, 4*g + r, 64);

  bf16* ob = f ? (bf16*)dout : obf;
  size_t orow = (size_t)(b*NQ + qrow0 + 4*g);
  #pragma unroll
  for (int r = 0; r < 4; r++){
    float iv = 1.0f / lT[r];
    ob[(orow + r)*CDIM + h*HD + m]      = f2b(O0[r] * iv);
    ob[(orow + r)*CDIM + h*HD + 16 + m] = f2b(O1[r] * iv);
  }
}

// ---------------------------------------------------------------------------
// final projection: A = (bf16 mode) d_out in-place | (fp32 mode) obf;
// output dtype per flag. Safe in place: each wave reads only its own 16 rows.
// ---------------------------------------------------------------------------
__global__ __launch_bounds__(256) void proj_kernel(
    const bf16* A0, const bf16* A1, const bf16* __restrict__ Wt,
    const bf16* __restrict__ bias, void* outp, const void* __restrict__ var)
{
  int f = detect_flag(var);
  const bf16* A = f ? A0 : A1;
  int wave = threadIdx.x >> 6, lane = threadIdx.x & 63;
  int m = lane & 15, g = lane >> 4;
  int row0 = (blockIdx.x*4 + wave)*16;
  bf8_t a[4];
  #pragma unroll
  for (int ks = 0; ks < 4; ks++)
    a[ks] = *(const bf8_t*)(A + (size_t)(row0 + m)*CDIM + 8*g + 32*ks);
  f4_t acc[8];
  mfma_row(a, Wt, m, g, acc);
  #pragma unroll
  for (int ct = 0; ct < 8; ct++){
    int col = ct*16 + m;
    float bv = b2f(bias[col]);
    #pragma unroll
    for (int r = 0; r < 4; r++){
      size_t oi = (size_t)(row0 + 4*g + r)*CDIM + col;
      float v = acc[ct][r] + bv;
      if (f) ((bf16*)outp)[oi]  = f2b(v);
      else   ((float*)outp)[oi] = v;
    }
  }
}

// ---------------------------------------------------------------------------
extern "C" void kernel_launch(void* const* d_in, const int* in_sizes, int n_in,
                              void* d_out, int out_size, void* d_ws, size_t ws_size,
                              hipStream_t stream)
{
  const void* x   = d_in[0];
  const void* rel = d_in[1];
  const void* Wq  = d_in[2];
  const void* bq  = d_in[3];
  const void* Wk  = d_in[4];
  const void* bk  = d_in[5];
  const void* Wv  = d_in[6];
  const void* bv  = d_in[7];
  const void* cw  = d_in[8];
  const void* cb  = d_in[9];
  const void* gam = d_in[10];
  const void* bet = d_in[11];
  const void* mea = d_in[12];
  const void* var = d_in[13];
  const void* Wp  = d_in[14];
  const void* bp  = d_in[15];

  char* w = (char*)d_ws;
  auto alloc = [&](size_t bytes){
    char* p = w; w += (bytes + 255) & ~(size_t)255; return p;
  };
  bf16* Wqt = (bf16*)alloc(128*128*sizeof(bf16));
  bf16* Wkt = (bf16*)alloc(128*128*sizeof(bf16));
  bf16* Wvt = (bf16*)alloc(128*128*sizeof(bf16));
  bf16* Wpt = (bf16*)alloc(128*128*sizeof(bf16));
  bf16* bqs = (bf16*)alloc(128*sizeof(bf16));
  bf16* bks = (bf16*)alloc(128*sizeof(bf16));
  bf16* bvs = (bf16*)alloc(128*sizeof(bf16));
  bf16* bps = (bf16*)alloc(128*sizeof(bf16));
  float* cwf    = (float*)alloc(512*sizeof(float));
  float* inv    = (float*)alloc(128*sizeof(float));
  float* shift2 = (float*)alloc(128*sizeof(float));
  bf16* kbf = (bf16*)alloc((size_t)BATCH*NKV*CDIM*sizeof(bf16));
  bf16* vtb = (bf16*)alloc((size_t)BATCH*NKV*CDIM*sizeof(bf16));
  bf16* obf = (bf16*)alloc((size_t)BATCH*NQ*CDIM*sizeof(bf16)); // fp32-mode attn out

  prep_kernel<<<256, 256, 0, stream>>>(Wq, Wk, Wv, Wp, var, cw, cb, gam, bet, mea,
                                       bq, bk, bv, bp,
                                       Wqt, Wkt, Wvt, Wpt, bqs, bks, bvs, bps,
                                       cwf, inv, shift2);
  kvconv_kernel<<<98, 256, 0, stream>>>(x, var, cwf, inv, shift2,
                                        Wkt, Wvt, bks, bvs, kbf, vtb);
  dim3 ag(196, NHEAD, BATCH);
  attn_kernel<<<ag, 64, 0, stream>>>(x, Wqt, bqs, kbf, vtb, rel, var, d_out, obf);
  proj_kernel<<<392, 256, 0, stream>>>((const bf16*)d_out, obf, Wpt, bps, d_out, var);
}

// Round 9
// 212.791 us; speedup vs baseline: 1.0718x; 1.0718x over previous
//
#include <hip/hip_runtime.h>
#include <hip/hip_bf16.h>

#define BATCH 8
#define NQ 3136
#define CDIM 128
#define NHEAD 4
#define HD 32
#define NKV 784
#define HIMG 56
#define SCALE 0.17677669529663687f

typedef __attribute__((ext_vector_type(8))) short bf8_t;   // 8 x bf16 (4 VGPRs)
typedef __attribute__((ext_vector_type(4))) float f4_t;    // 4 x fp32

using bf16 = __hip_bfloat16;
using u16  = unsigned short;

static __device__ __forceinline__ float b2f(bf16 v){ return __bfloat162float(v); }
static __device__ __forceinline__ bf16  f2b(float v){ return __float2bfloat16(v); }
static __device__ __forceinline__ short f2s(float v){
  union { bf16 b; short s; } u; u.b = f2b(v); return u.s;
}
static __device__ __forceinline__ float u16f(u16 x){
  union { u16 u; bf16 b; } c; c.u = x; return b2f(c.b);
}
// dual-dtype scalar load: f=1 -> bf16, f=0 -> fp32
static __device__ __forceinline__ float ld1(const void* p, size_t i, int f){
  return f ? b2f(((const bf16*)p)[i]) : ((const float*)p)[i];
}
// dual-dtype 4-element load (8B bf16 / 16B fp32)
static __device__ __forceinline__ float4 ld4f(const void* p, size_t i, int f){
  if (f){
    ushort4 u = *(const ushort4*)((const bf16*)p + i);
    return make_float4(u16f(u.x), u16f(u.y), u16f(u.z), u16f(u.w));
  }
  return *(const float4*)((const float*)p + i);
}
// dual-dtype 8-element fragment load (16B-aligned in both modes)
static __device__ __forceinline__ bf8_t ld8(const void* p, size_t i, int f){
  if (f) return *(const bf8_t*)((const bf16*)p + i);
  const float* fp = (const float*)p + i;
  float4 a = *(const float4*)fp;
  float4 b = *(const float4*)(fp + 4);
  bf8_t r;
  r[0]=f2s(a.x); r[1]=f2s(a.y); r[2]=f2s(a.z); r[3]=f2s(a.w);
  r[4]=f2s(b.x); r[5]=f2s(b.y); r[6]=f2s(b.z); r[7]=f2s(b.w);
  return r;
}
// Inline dtype detect from bn_var (~U[0.5,1.5]); wave-uniform, ~free (256B L2-hot).
static __device__ __forceinline__ int detect_flag(const void* var_raw){
  const u16* h = (const u16*)var_raw;
  int lane = threadIdx.x & 63;
  bool ok = true;
  #pragma unroll
  for (int t = 0; t < 2; t++){
    union { u16 u; bf16 b; } cv; cv.u = h[lane + 64*t];
    float v = b2f(cv.b);
    ok = ok && (v > 0.3f) && (v < 1.7f);
  }
  return (__ballot(ok) == ~0ull) ? 1 : 0;
}

// shared MFMA row core: acc[8] (16 rows x 128 cols) from prepped A-frags
static __device__ __forceinline__ void mfma_row(
    const bf8_t a[4], const bf16* __restrict__ Wt, int m, int g, f4_t acc[8])
{
  #pragma unroll
  for (int ct = 0; ct < 8; ct++){
    f4_t c = {0.f,0.f,0.f,0.f};
    const bf16* bp = Wt + (size_t)(ct*16 + m)*CDIM + 8*g;
    #pragma unroll
    for (int ks = 0; ks < 4; ks++){
      bf8_t b = *(const bf8_t*)(bp + 32*ks);
      c = __builtin_amdgcn_mfma_f32_16x16x32_bf16(a[ks], b, c, 0,0,0);
    }
    acc[ct] = c;
  }
}

// ---------------------------------------------------------------------------
// prep: weight transposes, SCALE folded into Wqt/bqs; small params; BN fold.
// cwf stored transposed [k][c] (k=tap 0..3, c=channel) for float4 loads.
// ---------------------------------------------------------------------------
__global__ __launch_bounds__(256) void prep_kernel(
    const void* __restrict__ Wq, const void* __restrict__ Wk,
    const void* __restrict__ Wv, const void* __restrict__ Wp,
    const void* __restrict__ var, const void* __restrict__ cw,
    const void* __restrict__ cb, const void* __restrict__ gam,
    const void* __restrict__ bet, const void* __restrict__ mea,
    const void* __restrict__ bq, const void* __restrict__ bk,
    const void* __restrict__ bv, const void* __restrict__ bp,
    bf16* __restrict__ Wqt, bf16* __restrict__ Wkt,
    bf16* __restrict__ Wvt, bf16* __restrict__ Wpt,
    bf16* __restrict__ bqs, bf16* __restrict__ bks,
    bf16* __restrict__ bvs, bf16* __restrict__ bps,
    float* __restrict__ cwf, float* __restrict__ inv, float* __restrict__ shift2)
{
  int f = detect_flag(var);
  int idx = blockIdx.x*256 + threadIdx.x;   // 4 * 16384
  int mat = idx >> 14;
  int e   = idx & 16383;                    // dst element: o=e>>7, i=e&127
  int o = e >> 7, i = e & 127;
  const void* src; bf16* dst; float s = 1.f;
  if      (mat == 0){ src = Wq; dst = Wqt; s = SCALE; }
  else if (mat == 1){ src = Wk; dst = Wkt; }
  else if (mat == 2){ src = Wv; dst = Wvt; }
  else              { src = Wp; dst = Wpt; }
  dst[e] = f2b(ld1(src, (size_t)i*128 + o, f) * s);

  if (blockIdx.x == 0){
    int t = threadIdx.x;
    // cw layout (C,1,2,2) = c*4+k  ->  cwf[k*128 + c]
    { int e2 = t;       cwf[(e2&3)*128 + (e2>>2)] = ld1(cw, e2, f); }
    { int e2 = t + 256; cwf[(e2&3)*128 + (e2>>2)] = ld1(cw, e2, f); }
    if (t < 128){
      bqs[t] = f2b(ld1(bq, t, f) * SCALE);
      bks[t] = f2b(ld1(bk, t, f));
      bvs[t] = f2b(ld1(bv, t, f));
      bps[t] = f2b(ld1(bp, t, f));
      float iv = ld1(gam, t, f) * rsqrtf(ld1(var, t, f) + 1e-5f);
      inv[t] = iv;
      shift2[t] = ld1(bet, t, f) - ld1(mea, t, f) * iv + ld1(cb, t, f) * iv;
    }
  }
}

// ---------------------------------------------------------------------------
// kvconv: blocks [0,196) = fused conv2x2s2+BN (32 rows -> LDS) + K/V GEMMs
//         (waves 0-1 = K rows 0-15/16-31, waves 2-3 = V).
//         blocks [196, 196+4802) = rel fp32 -> bf16 convert (fp32 mode only).
// xr never touches global memory. One launch replaces conv+q+convert+kv.
// ---------------------------------------------------------------------------
__global__ __launch_bounds__(256) void kvconv_kernel(
    const void* __restrict__ x, const void* __restrict__ var,
    const float* __restrict__ cwf, const float* __restrict__ inv,
    const float* __restrict__ shift2,
    const bf16* __restrict__ Wkt, const bf16* __restrict__ Wvt,
    const bf16* __restrict__ bks, const bf16* __restrict__ bvs,
    bf16* __restrict__ kbf, bf16* __restrict__ vtb,
    const void* __restrict__ rel, bf16* __restrict__ relb)
{
  int f = detect_flag(var);
  __shared__ bf16 xl[32*136];
  if (blockIdx.x < 196){
    int row0 = blockIdx.x*32;            // global row = b*NKV + kv
    #pragma unroll
    for (int it = 0; it < 4; it++){
      int s  = it*256 + threadIdx.x;     // 0..1023 = 32 rows x 32 ch-groups
      int lr = s >> 5;
      int c0 = (s & 31)*4;
      int t  = row0 + lr;
      int b  = t / NKV;
      int kv = t - b*NKV;
      int i = kv/28, j = kv - i*28;
      size_t base = (size_t)(b*NQ + 2*i*HIMG + 2*j)*CDIM + c0;
      float4 t0 = ld4f(x, base, f);
      float4 t1 = ld4f(x, base + CDIM, f);
      float4 t2 = ld4f(x, base + HIMG*CDIM, f);
      float4 t3 = ld4f(x, base + HIMG*CDIM + CDIM, f);
      float4 w0 = *(const float4*)(cwf + c0);
      float4 w1 = *(const float4*)(cwf + 128 + c0);
      float4 w2 = *(const float4*)(cwf + 256 + c0);
      float4 w3 = *(const float4*)(cwf + 384 + c0);
      float4 iv4 = *(const float4*)(inv + c0);
      float4 sh4 = *(const float4*)(shift2 + c0);
      union { u16 h[4]; uint2 u; } pk;
      float a;
      a = t0.x*w0.x + t1.x*w1.x + t2.x*w2.x + t3.x*w3.x; pk.h[0] = (u16)f2s(a*iv4.x + sh4.x);
      a = t0.y*w0.y + t1.y*w1.y + t2.y*w2.y + t3.y*w3.y; pk.h[1] = (u16)f2s(a*iv4.y + sh4.y);
      a = t0.z*w0.z + t1.z*w1.z + t2.z*w2.z + t3.z*w3.z; pk.h[2] = (u16)f2s(a*iv4.z + sh4.z);
      a = t0.w*w0.w + t1.w*w1.w + t2.w*w2.w + t3.w*w3.w; pk.h[3] = (u16)f2s(a*iv4.w + sh4.w);
      *(uint2*)(xl + lr*136 + c0) = pk.u;
    }
    __syncthreads();

    int wave = threadIdx.x >> 6, lane = threadIdx.x & 63;
    int m = lane & 15, g = lane >> 4;
    int r16 = (wave & 1)*16;             // 16-row tasks never straddle b (16|784)
    bf8_t a[4];
    #pragma unroll
    for (int ks = 0; ks < 4; ks++)
      a[ks] = *(const bf8_t*)(xl + (r16 + m)*136 + 8*g + 32*ks);
    int grow = row0 + r16;

    if (wave < 2){  // K projection -> kbf (B*NKV, C)
      f4_t acc[8];
      mfma_row(a, Wkt, m, g, acc);
      #pragma unroll
      for (int ct = 0; ct < 8; ct++){
        int col = ct*16 + m;
        float bv = b2f(bks[col]);
        #pragma unroll
        for (int r = 0; r < 4; r++)
          kbf[(size_t)(grow + 4*g + r)*CDIM + col] = f2b(acc[ct][r] + bv);
      }
    } else {        // V projection -> vtb transposed (B,H,D,NKV)
      f4_t acc[8];
      mfma_row(a, Wvt, m, g, acc);
      int b2  = grow / NKV;
      int kv0 = grow - b2*NKV + 4*g;
      #pragma unroll
      for (int ct = 0; ct < 8; ct++){
        int col = ct*16 + m;
        float bv = b2f(bvs[col]);
        int h = col >> 5, d = col & 31;
        union { bf16 hh[4]; uint2 u; } pk;
        #pragma unroll
        for (int r = 0; r < 4; r++) pk.hh[r] = f2b(acc[ct][r] + bv);
        *(uint2*)(vtb + (size_t)((b2*NHEAD + h)*HD + d)*NKV + kv0) = pk.u;
      }
    }
  } else {
    if (f) return;   // bf16 mode: attn reads original rel directly
    int bi = blockIdx.x - 196;                 // 0..4801
    size_t gid = ((size_t)bi*256 + threadIdx.x)*8;  // 8 elems/thread
    const float* fp = (const float*)rel + gid;
    float4 a  = *(const float4*)fp;
    float4 b4 = *(const float4*)(fp + 4);
    union { u16 hh[8]; uint4 u4; } pk;
    pk.hh[0]=(u16)f2s(a.x);  pk.hh[1]=(u16)f2s(a.y);
    pk.hh[2]=(u16)f2s(a.z);  pk.hh[3]=(u16)f2s(a.w);
    pk.hh[4]=(u16)f2s(b4.x); pk.hh[5]=(u16)f2s(b4.y);
    pk.hh[6]=(u16)f2s(b4.z); pk.hh[7]=(u16)f2s(b4.w);
    *(uint4*)(relb + gid) = pk.u4;
  }
}

// ---------------------------------------------------------------------------
// attn+proj fused: 4-wave blocks, wave = head. Per wave: fused Q projection,
// then the r7 barrier-free pipeline (swapped QK^T, K & rel register-prefetch
// one chunk ahead, early V, defer-rescale softmax, P via wave-local LDS
// roundtrip). Epilogue: sync, stage normalized 16x128 O-tile in LDS, sync,
// each wave computes its 32-col slice of O@Wp+bp (8 MFMAs) and writes the
// FINAL output directly (proj kernel + obf round-trip deleted).
// Grid (200, 8): x=qt (196 valid), y=b; b-stride 200 % 8 == 0 -> all 8
// batch-copies of a rel tile land on the same XCD L2 (bf16 relb: 2.5MB/XCD,
// L2-resident — the r8 fp32 regression showed 4.9MB/XCD thrashes).
// ---------------------------------------------------------------------------
template<int RM> struct RelV { using T = float4; };
template<> struct RelV<1> { using T = uint2; };

template<int RM>
static __device__ __forceinline__ typename RelV<RM>::T relld(const void* relp, int off){
  if constexpr (RM == 1) return *(const uint2*)((const bf16*)relp + off);
  else                   return *(const float4*)((const float*)relp + off);
}
template<int RM>
static __device__ __forceinline__ float relget(const typename RelV<RM>::T& v, int r){
  if constexpr (RM == 1){
    union { uint2 u; u16 h[4]; } c; c.u = v;
    return u16f(c.h[r]);
  } else {
    return r == 0 ? v.x : (r == 1 ? v.y : (r == 2 ? v.z : v.w));
  }
}
template<int RM>
static __device__ __forceinline__ void ldrel8(
    typename RelV<RM>::T rl[8], const void* relp, int off){
  #pragma unroll
  for (int t = 0; t < 8; t++) rl[t] = relld<RM>(relp, off + 16*t);
}

// PF: 2 = prefetch full next chunk, 1 = prefetch tail (1 frag)
template<int RM, int PF>
static __device__ __forceinline__ void chunk128(
    int kv0,
    typename RelV<RM>::T rl[8], bf8_t kc[8],
    typename RelV<RM>::T rln[8], bf8_t kn[8],
    const void* __restrict__ relp, const bf16* __restrict__ kbase,
    const bf16* __restrict__ vb0, const bf16* __restrict__ vb1,
    bf16* __restrict__ pl, int m, int g, bf8_t q8,
    float& m_run, float& l_run, f4_t& O0, f4_t& O1)
{
  // QK^T from register K (prefetched during previous chunk)
  f4_t s[8];
  #pragma unroll
  for (int t = 0; t < 8; t++){
    f4_t z = {0.f,0.f,0.f,0.f};
    s[t] = __builtin_amdgcn_mfma_f32_16x16x32_bf16(kc[t], q8, z, 0,0,0);
  }
  // issue next-chunk K loads: latency hides under this chunk's softmax+PV
  if constexpr (PF == 2){
    #pragma unroll
    for (int t = 0; t < 8; t++)
      kn[t] = *(const bf8_t*)(kbase + (size_t)(kv0 + 128 + t*16)*CDIM);
  } else if constexpr (PF == 1){
    kn[0] = *(const bf8_t*)(kbase + (size_t)768*CDIM);
  }
  // this-chunk V: consumed after softmax (~200+ cy of slack)
  bf8_t v0[4], v1[4];
  #pragma unroll
  for (int ks = 0; ks < 4; ks++){
    v0[ks] = *(const bf8_t*)(vb0 + kv0 + ks*32 + 8*g);
    v1[ks] = *(const bf8_t*)(vb1 + kv0 + ks*32 + 8*g);
  }
  // rel add from prefetched registers; then issue next-chunk rel loads
  #pragma unroll
  for (int t = 0; t < 8; t++)
    #pragma unroll
    for (int r = 0; r < 4; r++)
      s[t][r] += relget<RM>(rl[t], r);
  if constexpr (PF == 2) ldrel8<RM>(rln, relp, kv0 + 128 + 4*g);
  else if constexpr (PF == 1) rln[0] = relld<RM>(relp, 768 + 4*g);
  // online softmax, one q (=m) per lane
  float vmax = s[0][0];
  #pragma unroll
  for (int t = 0; t < 8; t++)
    #pragma unroll
    for (int r = 0; r < 4; r++)
      if (t + r > 0) vmax = fmaxf(vmax, s[t][r]);
  vmax = fmaxf(vmax, __shfl_xor(vmax, 16, 64));
  vmax = fmaxf(vmax, __shfl_xor(vmax, 32, 64));
  // T13 defer-rescale: only rescale when the running max grows >THR.
  if (!__all(vmax <= m_run + 8.f)){
    float mn = fmaxf(m_run, vmax);
    float al = __expf(m_run - mn);
    m_run = mn;
    l_run *= al;
    float alT[4];
    #pragma unroll
    for (int r = 0; r < 4; r++) alT[r] = __shfl(al, 4*g + r, 64);
    #pragma unroll
    for (int r = 0; r < 4; r++){ O0[r] *= alT[r]; O1[r] *= alT[r]; }
  }
  // P: exp, lane-partial l, pack 4 bf16 -> b64 LDS write per t
  float lsum = 0.f;
  #pragma unroll
  for (int t = 0; t < 8; t++){
    union { u16 h[4]; uint2 u; } pk;
    #pragma unroll
    for (int r = 0; r < 4; r++){
      float p = __expf(s[t][r] - m_run);
      lsum += p;
      pk.h[r] = (u16)f2s(p);
    }
    *(uint2*)(pl + m*136 + t*16 + 4*g) = pk.u;
  }
  l_run += lsum;
  // PV: wave-local LDS roundtrip (same-wave in-order) + register V
  #pragma unroll
  for (int ks = 0; ks < 4; ks++){
    bf8_t a8 = *(const bf8_t*)(pl + m*136 + ks*32 + 8*g);
    O0 = __builtin_amdgcn_mfma_f32_16x16x32_bf16(a8, v0[ks], O0, 0,0,0);
    O1 = __builtin_amdgcn_mfma_f32_16x16x32_bf16(a8, v1[ks], O1, 0,0,0);
  }
}

template<int RM>
static __device__ __forceinline__ void attn_run(
    const void* __restrict__ relp, const bf16* __restrict__ kbase,
    const bf16* __restrict__ vb0, const bf16* __restrict__ vb1,
    bf16* __restrict__ pl, int m, int g,
    bf8_t q8, float& m_run, float& l_run, f4_t& O0, f4_t& O1)
{
  using RT = typename RelV<RM>::T;
  RT rlA[8], rlB[8];
  bf8_t kA[8], kB[8];
  ldrel8<RM>(rlA, relp, 4*g);
  #pragma unroll
  for (int t = 0; t < 8; t++)
    kA[t] = *(const bf8_t*)(kbase + (size_t)(t*16)*CDIM);

  chunk128<RM,2>(0,   rlA,kA, rlB,kB, relp,kbase,vb0,vb1,pl,m,g,q8,m_run,l_run,O0,O1);
  chunk128<RM,2>(128, rlB,kB, rlA,kA, relp,kbase,vb0,vb1,pl,m,g,q8,m_run,l_run,O0,O1);
  chunk128<RM,2>(256, rlA,kA, rlB,kB, relp,kbase,vb0,vb1,pl,m,g,q8,m_run,l_run,O0,O1);
  chunk128<RM,2>(384, rlB,kB, rlA,kA, relp,kbase,vb0,vb1,pl,m,g,q8,m_run,l_run,O0,O1);
  chunk128<RM,2>(512, rlA,kA, rlB,kB, relp,kbase,vb0,vb1,pl,m,g,q8,m_run,l_run,O0,O1);
  chunk128<RM,1>(640, rlB,kB, rlA,kA, relp,kbase,vb0,vb1,pl,m,g,q8,m_run,l_run,O0,O1);

  // ---- tail: kv 768..783 (K in kA[0], rel in rlA[0], prefetched) ----
  {
    f4_t z = {0.f,0.f,0.f,0.f};
    f4_t s1 = __builtin_amdgcn_mfma_f32_16x16x32_bf16(kA[0], q8, z, 0,0,0);
    #pragma unroll
    for (int r = 0; r < 4; r++) s1[r] += relget<RM>(rlA[0], r);
    float vmax = fmaxf(fmaxf(s1[0], s1[1]), fmaxf(s1[2], s1[3]));
    vmax = fmaxf(vmax, __shfl_xor(vmax, 16, 64));
    vmax = fmaxf(vmax, __shfl_xor(vmax, 32, 64));
    if (!__all(vmax <= m_run + 8.f)){
      float mn = fmaxf(m_run, vmax);
      float al = __expf(m_run - mn);
      m_run = mn;
      l_run *= al;
      float alT[4];
      #pragma unroll
      for (int r = 0; r < 4; r++) alT[r] = __shfl(al, 4*g + r, 64);
      #pragma unroll
      for (int r = 0; r < 4; r++){ O0[r] *= alT[r]; O1[r] *= alT[r]; }
    }
    union { u16 h[4]; uint2 u; } pk;
    float lsum = 0.f;
    #pragma unroll
    for (int r = 0; r < 4; r++){
      float p = __expf(s1[r] - m_run);
      lsum += p;
      pk.h[r] = (u16)f2s(p);
    }
    *(uint2*)(pl + m*136 + 4*g) = pk.u;
    l_run += lsum;
    bf8_t a8, v0, v1;
    if (g >= 2){        // kv >= 784: zero fragments in registers
      bf8_t z8 = {0,0,0,0,0,0,0,0};
      a8 = z8; v0 = z8; v1 = z8;
    } else {
      a8 = *(const bf8_t*)(pl + m*136 + 8*g);
      v0 = *(const bf8_t*)(vb0 + 768 + 8*g);
      v1 = *(const bf8_t*)(vb1 + 768 + 8*g);
    }
    O0 = __builtin_amdgcn_mfma_f32_16x16x32_bf16(a8, v0, O0, 0,0,0);
    O1 = __builtin_amdgcn_mfma_f32_16x16x32_bf16(a8, v1, O1, 0,0,0);
  }
}

// FB=0: rel bf16 (relb or bf16-input rel). FB=1: fp32-direct fallback.
template<int FB>
static __device__ __forceinline__ void attn_device(
    const void* __restrict__ x,
    const bf16* __restrict__ Wqt, const bf16* __restrict__ bqs,
    const bf16* __restrict__ Wpt, const bf16* __restrict__ bps,
    const bf16* __restrict__ kb, const bf16* __restrict__ vtb,
    const void* __restrict__ rel, const bf16* __restrict__ relb,
    const void* __restrict__ var, void* __restrict__ dout)
{
  int f = detect_flag(var);
  int wave = threadIdx.x >> 6, lane = threadIdx.x & 63;
  int m = lane & 15, g = lane >> 4;
  int qt = blockIdx.x, b = blockIdx.y;
  if (qt >= 196) return;
  int h = wave;                        // wave = head
  int qrow0 = qt*16;

  __shared__ bf16 Plds[4][16*136];     // 17408 B; per-wave regions
  bf16* pl = Plds[wave];

  // fused Q projection (wave-local LDS roundtrip; no barrier)
  bf8_t q8;
  {
    bf8_t xa[4];
    #pragma unroll
    for (int ks = 0; ks < 4; ks++)
      xa[ks] = ld8(x, (size_t)(b*NQ + qrow0 + m)*CDIM + 8*g + 32*ks, f);
    f4_t qc0 = {0.f,0.f,0.f,0.f}, qc1 = {0.f,0.f,0.f,0.f};
    const bf16* wp0 = Wqt + (size_t)(h*HD + m)*CDIM + 8*g;
    const bf16* wp1 = Wqt + (size_t)(h*HD + 16 + m)*CDIM + 8*g;
    #pragma unroll
    for (int ks = 0; ks < 4; ks++){
      bf8_t w0 = *(const bf8_t*)(wp0 + 32*ks);
      bf8_t w1 = *(const bf8_t*)(wp1 + 32*ks);
      qc0 = __builtin_amdgcn_mfma_f32_16x16x32_bf16(xa[ks], w0, qc0, 0,0,0);
      qc1 = __builtin_amdgcn_mfma_f32_16x16x32_bf16(xa[ks], w1, qc1, 0,0,0);
    }
    float bv0 = b2f(bqs[h*HD + m]);
    float bv1 = b2f(bqs[h*HD + 16 + m]);
    #pragma unroll
    for (int r = 0; r < 4; r++){
      pl[(4*g + r)*136 + m]      = f2b(qc0[r] + bv0);
      pl[(4*g + r)*136 + 16 + m] = f2b(qc1[r] + bv1);
    }
    q8 = *(const bf8_t*)(pl + m*136 + 8*g);
  }

  const bf16* kbase = kb  + (size_t)(b*NKV + m)*CDIM + h*HD + 8*g;
  const bf16* vb0   = vtb + (size_t)((b*NHEAD + h)*HD + m)*NKV;
  const bf16* vb1   = vtb + (size_t)((b*NHEAD + h)*HD + 16 + m)*NKV;
  size_t rrow = ((size_t)h*NQ + qrow0 + m)*(size_t)NKV;   // per-lane q = m

  float m_run = -1e30f, l_run = 0.f;
  f4_t O0 = {0.f,0.f,0.f,0.f}, O1 = {0.f,0.f,0.f,0.f};

  if constexpr (FB == 0){
    const void* rsrc = f ? (const void*)((const bf16*)rel + rrow)
                         : (const void*)(relb + rrow);
    attn_run<1>(rsrc, kbase, vb0, vb1, pl, m, g, q8, m_run, l_run, O0, O1);
  } else {
    if (f) attn_run<1>((const void*)((const bf16*)rel + rrow), kbase, vb0, vb1,
                       pl, m, g, q8, m_run, l_run, O0, O1);
    else   attn_run<0>((const void*)((const float*)rel + rrow), kbase, vb0, vb1,
                       pl, m, g, q8, m_run, l_run, O0, O1);
  }

  // finalize l across g-lanes (q=m layout), transpose to O-row layout
  l_run += __shfl_xor(l_run, 16, 64);
  l_run += __shfl_xor(l_run, 32, 64);
  float lT[4];
  #pragma unroll
  for (int r = 0; r < 4; r++) lT[r] = __shfl(l_run, 4*g + r, 64);

  // ---- fused output projection ----
  __syncthreads();                     // all waves done with their pl
  bf16* Ot = &Plds[0][0];              // shared 16x128 O-tile (stride 136)
  #pragma unroll
  for (int r = 0; r < 4; r++){
    float iv = 1.0f / lT[r];
    Ot[(4*g + r)*136 + h*HD + m]      = f2b(O0[r] * iv);
    Ot[(4*g + r)*136 + h*HD + 16 + m] = f2b(O1[r] * iv);
  }
  __syncthreads();

  bf8_t a[4];
  #pragma unroll
  for (int ks = 0; ks < 4; ks++)
    a[ks] = *(const bf8_t*)(Ot + m*136 + 8*g + 32*ks);
  #pragma unroll
  for (int cgi = 0; cgi < 2; cgi++){
    int cg = 2*h + cgi;                // this wave's 2 col-groups of 16
    f4_t c = {0.f,0.f,0.f,0.f};
    const bf16* bp = Wpt + (size_t)(cg*16 + m)*CDIM + 8*g;
    #pragma unroll
    for (int ks = 0; ks < 4; ks++){
      bf8_t w = *(const bf8_t*)(bp + 32*ks);
      c = __builtin_amdgcn_mfma_f32_16x16x32_bf16(a[ks], w, c, 0,0,0);
    }
    int col = cg*16 + m;
    float bv = b2f(bps[col]);
    #pragma unroll
    for (int r = 0; r < 4; r++){
      size_t oi = (size_t)(b*NQ + qrow0 + 4*g + r)*CDIM + col;
      float v = c[r] + bv;
      if (f) ((bf16*)dout)[oi]  = f2b(v);
      else   ((float*)dout)[oi] = v;
    }
  }
}

__global__ __launch_bounds__(256) void attn_kernel(
    const void* __restrict__ x,
    const bf16* __restrict__ Wqt, const bf16* __restrict__ bqs,
    const bf16* __restrict__ Wpt, const bf16* __restrict__ bps,
    const bf16* __restrict__ kb, const bf16* __restrict__ vtb,
    const void* __restrict__ rel, const bf16* __restrict__ relb,
    const void* __restrict__ var, void* __restrict__ dout)
{
  attn_device<0>(x, Wqt, bqs, Wpt, bps, kb, vtb, rel, relb, var, dout);
}

__global__ __launch_bounds__(256) void attn_kernel_fb(
    const void* __restrict__ x,
    const bf16* __restrict__ Wqt, const bf16* __restrict__ bqs,
    const bf16* __restrict__ Wpt, const bf16* __restrict__ bps,
    const bf16* __restrict__ kb, const bf16* __restrict__ vtb,
    const void* __restrict__ rel, const bf16* __restrict__ relb,
    const void* __restrict__ var, void* __restrict__ dout)
{
  attn_device<1>(x, Wqt, bqs, Wpt, bps, kb, vtb, rel, relb, var, dout);
}

// ---------------------------------------------------------------------------
extern "C" void kernel_launch(void* const* d_in, const int* in_sizes, int n_in,
                              void* d_out, int out_size, void* d_ws, size_t ws_size,
                              hipStream_t stream)
{
  const void* x   = d_in[0];
  const void* rel = d_in[1];
  const void* Wq  = d_in[2];
  const void* bq  = d_in[3];
  const void* Wk  = d_in[4];
  const void* bk  = d_in[5];
  const void* Wv  = d_in[6];
  const void* bv  = d_in[7];
  const void* cw  = d_in[8];
  const void* cb  = d_in[9];
  const void* gam = d_in[10];
  const void* bet = d_in[11];
  const void* mea = d_in[12];
  const void* var = d_in[13];
  const void* Wp  = d_in[14];
  const void* bp  = d_in[15];

  char* w = (char*)d_ws;
  auto alloc = [&](size_t bytes){
    char* p = w; w += (bytes + 255) & ~(size_t)255; return p;
  };
  bf16* Wqt = (bf16*)alloc(128*128*sizeof(bf16));
  bf16* Wkt = (bf16*)alloc(128*128*sizeof(bf16));
  bf16* Wvt = (bf16*)alloc(128*128*sizeof(bf16));
  bf16* Wpt = (bf16*)alloc(128*128*sizeof(bf16));
  bf16* bqs = (bf16*)alloc(128*sizeof(bf16));
  bf16* bks = (bf16*)alloc(128*sizeof(bf16));
  bf16* bvs = (bf16*)alloc(128*sizeof(bf16));
  bf16* bps = (bf16*)alloc(128*sizeof(bf16));
  float* cwf    = (float*)alloc(512*sizeof(float));
  float* inv    = (float*)alloc(128*sizeof(float));
  float* shift2 = (float*)alloc(128*sizeof(float));
  bf16* kbf = (bf16*)alloc((size_t)BATCH*NKV*CDIM*sizeof(bf16));
  bf16* vtb = (bf16*)alloc((size_t)BATCH*NKV*CDIM*sizeof(bf16));

  // rel bf16 copy (fp32 mode): 4*3136*784*2 = 19.7 MB — keeps the per-XCD
  // rel working set (2.5MB) inside the 4MB L2 (r8's fp32-direct thrashed).
  size_t relb_bytes = (size_t)NHEAD*NQ*NKV*sizeof(bf16);
  bf16* relb = nullptr;
  if (((char*)d_ws + ws_size) - w >= (ptrdiff_t)(relb_bytes + 256))
    relb = (bf16*)alloc(relb_bytes);

  int rblk = relb ? 4802 : 0;   // 9,834,496 / 2048 elems per block

  prep_kernel<<<256, 256, 0, stream>>>(Wq, Wk, Wv, Wp, var, cw, cb, gam, bet, mea,
                                       bq, bk, bv, bp,
                                       Wqt, Wkt, Wvt, Wpt, bqs, bks, bvs, bps,
                                       cwf, inv, shift2);
  kvconv_kernel<<<196 + rblk, 256, 0, stream>>>(
      x, var, cwf, inv, shift2, Wkt, Wvt, bks, bvs, kbf, vtb, rel, relb);
  dim3 ag(200, BATCH);
  if (relb)
    attn_kernel<<<ag, 256, 0, stream>>>(
        x, Wqt, bqs, Wpt, bps, kbf, vtb, rel, relb, var, d_out);
  else
    attn_kernel_fb<<<ag, 256, 0, stream>>>(
        x, Wqt, bqs, Wpt, bps, kbf, vtb, rel, relb, var, d_out);
}